// Round 1
// baseline (232.828 us; speedup 1.0000x reference)
//
#include <hip/hip_runtime.h>

// SSIM map, fused single kernel.
// Shapes fixed by the problem: B=16, C=3, H=W=512, window=11 (separable gaussian).
// Separable depthwise conv: horizontal 11-tap pass -> LDS, vertical 11-tap pass
// -> registers, then the SSIM formula. 5 conv fields: x, y, x*x, y*y, x*y.

#define HH   512
#define WW   512
#define BC   48          // B*C planes
#define TX   32          // output tile width
#define TY   32          // output tile height
#define HALO 5
#define IX   (TX + 2*HALO)   // 42
#define IY   (TY + 2*HALO)   // 42
#define NTH  256

__global__ __launch_bounds__(NTH) void ssim_kernel(
    const float* __restrict__ x, const float* __restrict__ y,
    float* __restrict__ out)
{
    // 42*42*2 floats inputs (13.8 KB) + 5*42*32 floats h-conv (26.9 KB) = ~41 KB
    __shared__ float sx[IY][IX];
    __shared__ float sy[IY][IX];
    __shared__ float hf[5][IY][TX];

    // fp32-normalized gaussian, sigma=1.5, K=11 (matches reference to ~1e-7)
    const float g[11] = {
        0.00102838f, 0.00759875f, 0.03600077f, 0.10936069f, 0.21300553f,
        0.26601172f,
        0.21300553f, 0.10936069f, 0.03600077f, 0.00759875f, 0.00102838f};

    const int t    = threadIdx.x;
    const int bc   = blockIdx.z;
    const int col0 = blockIdx.x * TX;
    const int row0 = blockIdx.y * TY;
    const float* __restrict__ xp = x + (size_t)bc * HH * WW;
    const float* __restrict__ yp = y + (size_t)bc * HH * WW;

    // ---- Stage 1: global -> LDS halo tiles (zero-pad at image borders) ----
    for (int i = t; i < IY * IX; i += NTH) {
        const int r = i / IX, c = i % IX;
        const int gr = row0 + r - HALO;
        const int gc = col0 + c - HALO;
        float vx = 0.f, vy = 0.f;
        if (gr >= 0 && gr < HH && gc >= 0 && gc < WW) {
            const int gi = gr * WW + gc;
            vx = xp[gi];
            vy = yp[gi];
        }
        sx[r][c] = vx;
        sy[r][c] = vy;
    }
    __syncthreads();

    // ---- Stage 2: horizontal 11-tap conv of 5 fields, IY rows x TX cols ----
    for (int i = t; i < IY * TX; i += NTH) {
        const int r = i / TX, c = i % TX;
        float hx = 0.f, hy = 0.f, hxx = 0.f, hyy = 0.f, hxy = 0.f;
#pragma unroll
        for (int k = 0; k < 11; ++k) {
            const float w  = g[k];
            const float vx = sx[r][c + k];
            const float vy = sy[r][c + k];
            hx  += w * vx;
            hy  += w * vy;
            hxx += w * (vx * vx);
            hyy += w * (vy * vy);
            hxy += w * (vx * vy);
        }
        hf[0][r][c] = hx;
        hf[1][r][c] = hy;
        hf[2][r][c] = hxx;
        hf[3][r][c] = hyy;
        hf[4][r][c] = hxy;
    }
    __syncthreads();

    // ---- Stage 3: vertical 11-tap conv + SSIM formula, 4 rows/thread ----
    const int ocol  = t % TX;       // 0..31
    const int orow0 = t / TX;       // 0..7
    float* __restrict__ op = out + (size_t)bc * HH * WW;
    const float C1f = 1e-4f;        // 0.01^2
    const float C2f = 9e-4f;        // 0.03^2
#pragma unroll
    for (int j = 0; j < TY / (NTH / TX); ++j) {
        const int orow = orow0 + j * (NTH / TX);
        float mu1 = 0.f, mu2 = 0.f, ex2 = 0.f, ey2 = 0.f, exy = 0.f;
#pragma unroll
        for (int k = 0; k < 11; ++k) {
            const float w = g[k];
            mu1 += w * hf[0][orow + k][ocol];
            mu2 += w * hf[1][orow + k][ocol];
            ex2 += w * hf[2][orow + k][ocol];
            ey2 += w * hf[3][orow + k][ocol];
            exy += w * hf[4][orow + k][ocol];
        }
        const float mu1sq = mu1 * mu1;
        const float mu2sq = mu2 * mu2;
        const float mu12  = mu1 * mu2;
        const float s1    = ex2 - mu1sq;   // sigma1_sq
        const float s2    = ey2 - mu2sq;   // sigma2_sq
        const float s12   = exy - mu12;    // sigma1_sigma2
        const float num = (2.f * mu12 + C1f) * (2.f * s12 + C2f);
        const float den = (mu1sq + mu2sq + C1f) * (s1 + s2 + C2f);
        op[(row0 + orow) * WW + (col0 + ocol)] = num / den;
    }
}

extern "C" void kernel_launch(void* const* d_in, const int* in_sizes, int n_in,
                              void* d_out, int out_size, void* d_ws, size_t ws_size,
                              hipStream_t stream) {
    const float* img_out    = (const float*)d_in[0];
    const float* img_target = (const float*)d_in[1];
    // d_in[2] is window_size==11; fixed by the problem, baked into the kernel.
    float* out = (float*)d_out;

    dim3 grid(WW / TX, HH / TY, BC);   // 16 x 16 x 48 = 12288 blocks
    ssim_kernel<<<grid, NTH, 0, stream>>>(img_out, img_target, out);
}